// Round 11
// baseline (202.976 us; speedup 1.0000x reference)
//
#include <hip/hip_runtime.h>
#include <math.h>
#include <stdint.h>

// Problem: M=131072 rows, N=4000 verts (padded to 4096), D=16.
#define M_ROWS   131072
#define N_VERTS  4000
#define N_PAD    4096
#define D_DIM    16
#define N_TILES  (N_PAD / 32)          // 128 n-tiles of 32 verts (4000 = 125*32 exactly)
#define TILE_B   2048                  // per tile: yh 1KB | yl 1KB
#define CHUNK_T  8                     // tiles per LDS chunk
#define CHUNK_B  (CHUNK_T * TILE_B)    // 16384 B per chunk
#define N_CHUNKS (N_TILES / CHUNK_T)   // 16

#define SCORE_BIAS 128.0f
// R11: EXACT fp32 score tracking (no packed-key truncation). Ambiguity test
// error budget is pure arithmetic: dropped al*yl cross term <= 4.9e-4,
// MFMA fp32 accum ~2e-4, ysq exact fp32 -> delta <= 0.7e-3.
// TIE_EPS = 0.002 >= 2.8x delta. Any EXACT fp32 tie gives second-best ==
// best -> 0 <= EPS -> auto-flagged -> rescan resolves ordering, so the
// screen's argmin col/tile ordering is irrelevant for flagged rows.
#define TIE_EPS  0.002f

// d_ws layout (bytes):
//   [0      .. 262144)  yfrag : N_TILES x 2048 B, fragment-ordered 32x32 data
//   [262144 .. 278528)  ysq   : N_PAD floats, bias+||y||^2 fp32 (pads 1e30)
//   [278528 .. 278532)  cnt
//   [278592 .. ...   )  list  : ambiguous row indices
#define WS_YFRAG_OFF 0
#define WS_YSQ_OFF   262144
#define WS_CNT_OFF   278528
#define WS_LIST_OFF  278592

typedef float    f32x16 __attribute__((ext_vector_type(16)));
typedef short    s16x8  __attribute__((ext_vector_type(8)));

__device__ __forceinline__ unsigned short f32_to_bf16_rne(float f) {
    unsigned int u = __float_as_uint(f);
    u = (u + 0x7fffu + ((u >> 16) & 1u)) >> 16;
    return (unsigned short)u;
}
__device__ __forceinline__ float bf16_to_f32(unsigned short h) {
    return __uint_as_float(((unsigned int)h) << 16);
}

// median(a,b,c) in one VALU op. Under the invariant a <= c this equals
// min(c, max(a, b)) -- the second-best update (float version; all scores
// finite, no NaN). Case check (b = new value v): v<a -> a; a<=v<=c -> v;
// v>c -> c. Invariant preserved: min(a,v) <= min(c, max(a,v)).
// [u32 version verified R4 absmax=0; identical algebra]
__device__ __forceinline__ float med3f(float a, float b, float c) {
    float d;
    asm("v_med3_f32 %0, %1, %2, %3" : "=v"(d) : "v"(a), "v"(b), "v"(c));
    return d;
}

// ---------------------------------------------------------------------------
// Kernel 1: pack Y into 32x32-MFMA fragment order + fp32 biased ysq.
// B-operand layout for mfma_f32_32x32x16_bf16 (verified R1/R2, absmax=0):
// B[n = lane&31][k = (lane>>5)*8 + j].
// Per tile T (32 verts): yh frag (64 lanes x 16B) | yl frag.
// One thread per (tile, lane) = 8192 threads.  [unchanged from R8, verified]
// ---------------------------------------------------------------------------
__global__ void pack_y_kernel(const float* __restrict__ verts,
                              char* __restrict__ yfrag,
                              float* __restrict__ ysq,
                              int* __restrict__ cnt) {
    const int tid = blockIdx.x * blockDim.x + threadIdx.x;   // 0..8191
    if (tid == 0) *cnt = 0;

    const int T   = tid >> 6;
    const int l   = tid & 63;
    const int col = l & 31;
    const int h   = l >> 5;
    const int n   = T * 32 + col;
    const int d0  = h * 8;

    float v[8];
    if (n < N_VERTS) {
        const float* y = verts + (size_t)n * D_DIM + d0;
#pragma unroll
        for (int j = 0; j < 8; ++j) v[j] = y[j];
    } else {
#pragma unroll
        for (int j = 0; j < 8; ++j) v[j] = 0.f;
    }
    s16x8 fh, fl;
#pragma unroll
    for (int j = 0; j < 8; ++j) {
        const unsigned short hh = f32_to_bf16_rne(v[j]);
        fh[j] = (short)hh;
        fl[j] = (short)f32_to_bf16_rne(v[j] - bf16_to_f32(hh));
    }
    char* tb = yfrag + (size_t)T * TILE_B + (size_t)l * 16;
    *(s16x8*)(tb)        = fh;
    *(s16x8*)(tb + 1024) = fl;

    // ysq: fp32, bias baked in; pad columns get 1e30 so they never win.
    if (tid < N_PAD) {
        float ys;
        if (tid < N_VERTS) {
            ys = SCORE_BIAS;
            const float* y = verts + (size_t)tid * D_DIM;
#pragma unroll
            for (int d = 0; d < D_DIM; ++d) ys = fmaf(y[d], y[d], ys);
        } else {
            ys = 1e30f;
        }
        ysq[tid] = ys;
    }
}

// ---------------------------------------------------------------------------
// Kernel 2 (MFMA screen, 32x32x16): 512 thr = 8 waves, wave = 32 rows x all n.
// R4 loop structure (verified): CHUNK_T=8, launch_bounds(512,4), reg-prefetch
// double-buffered LDS, one barrier per chunk. ysq via fp32 acc init (R8).
//
// R11: EXACT fp32 best/second/tile tracking, no packed keys. Per r:
//   sec = med3f(best_old, v, sec); tile = (v < best_old) ? tcur : tile;
//   best = fminf(best_old, v).
// Strict < keeps earliest tile within a column; cross-column exact ties are
// auto-flagged (secondAll==best -> amb) so col order is irrelevant.
// Epilogue: 3 barriered LDS passes (scores -> tiles -> seconds) reusing s_buf.
//
// History: R6 do NOT raise min-waves (VGPR squeeze -> spill). R3:
// global_load_lds staging FAILED correctness. R5: 2-tile ILP regressed.
// R9/R10: AGPR-shuttle theory refuted (VGPR pins + asm-VGPR MFMA both null).
// `#pragma unroll 1`: full unroll -> spill (R1). Spill tripwire: FETCH <20MB.
// ---------------------------------------------------------------------------
__global__ __launch_bounds__(512, 4) void mfma_screen_kernel(
    const float* __restrict__ x_all,    // (M,16)
    const float* __restrict__ colors,   // (N,3)
    const char* __restrict__ yfrag,     // N_TILES x 2048 B
    const float* __restrict__ ysqg,     // N_PAD fp32 (biased)
    float* __restrict__ out,            // (M,3)
    int* __restrict__ cnt,
    int* __restrict__ list,
    int list_cap)
{
    __shared__ __align__(16) char  s_buf[2 * CHUNK_B];   // 32 KB (reused for reduce)
    __shared__ __align__(16) float s_ysq[N_PAD];         // 16 KB

    const int tid  = threadIdx.x;
    const int wave = tid >> 6;
    const int lane = tid & 63;
    const int col  = lane & 31;          // A row / B col / C-D col
    const int h    = lane >> 5;          // k-half select
    const int rowBase = blockIdx.x * 256 + wave * 32;

    // --- A fragments (built once). Lane supplies A[m=col][k=h*8+j].
    const float* xr = x_all + (size_t)(rowBase + col) * D_DIM + h * 8;
    const float4 xa = *(const float4*)xr;
    const float4 xb = *(const float4*)(xr + 4);
    const float xv[8] = {xa.x, xa.y, xa.z, xa.w, xb.x, xb.y, xb.z, xb.w};
    s16x8 a1, a2;
#pragma unroll
    for (int j = 0; j < 8; ++j) {
        const float a = -2.0f * xv[j];
        const unsigned short hh = f32_to_bf16_rne(a);
        a1[j] = (short)hh;
        a2[j] = (short)f32_to_bf16_rne(a - bf16_to_f32(hh));
    }

    // --- Stage ysq once (1024 int4, 2 per thread). Fenced by first barrier.
    {
        const int4* g = (const int4*)ysqg;
        int4* s = (int4*)s_ysq;
        s[tid] = g[tid];
        s[tid + 512] = g[tid + 512];
    }
    // --- Prologue: chunk 0 -> buf0 (stride-16B per thread: conflict-free).
    const int4* gy = (const int4*)yfrag;
    int4 ra = gy[tid];
    int4 rb = gy[512 + tid];
    {
        int4* s = (int4*)s_buf;
        s[tid] = ra;
        s[512 + tid] = rb;
    }

    float    bestf[16], secf[16];
    uint32_t tidx[16];
#pragma unroll
    for (int r = 0; r < 16; ++r) { bestf[r] = 3e38f; secf[r] = 3e38f; tidx[r] = 0; }

    for (int ch = 0; ch < N_CHUNKS; ++ch) {
        // Prefetch next chunk into regs BEFORE the barrier (latency overlap).
        if (ch + 1 < N_CHUNKS) {
            ra = gy[(ch + 1) * 1024 + tid];
            rb = gy[(ch + 1) * 1024 + 512 + tid];
        }
        __syncthreads();   // buf[ch&1] writes (prev iter / prologue) visible

        const char*  bb    = s_buf + (ch & 1) * CHUNK_B + lane * 16;
        const float* ysrow = s_ysq + ch * CHUNK_T * 32 + col;
#pragma unroll 1
        for (int t = 0; t < CHUNK_T; ++t) {
            const s16x8 byh = *(const s16x8*)(bb + t * TILE_B);          // conflict-free
            const s16x8 byl = *(const s16x8*)(bb + t * TILE_B + 1024);
            const float ysn = ysrow[t * 32];   // per-lane scalar; lanes l/l+32 broadcast
            f32x16 acc;
#pragma unroll
            for (int r = 0; r < 16; ++r) acc[r] = ysn;
            acc = __builtin_amdgcn_mfma_f32_32x32x16_bf16(a1, byh, acc, 0, 0, 0);
            acc = __builtin_amdgcn_mfma_f32_32x32x16_bf16(a2, byh, acc, 0, 0, 0);
            acc = __builtin_amdgcn_mfma_f32_32x32x16_bf16(a1, byl, acc, 0, 0, 0);
            const uint32_t tcur = (uint32_t)(ch * CHUNK_T + t);
#pragma unroll
            for (int r = 0; r < 16; ++r) {
                const float v  = acc[r];
                const float ob = bestf[r];
                secf[r]  = med3f(ob, v, secf[r]);       // = min(sec, max(best,v))
                tidx[r]  = (v < ob) ? tcur : tidx[r];   // strict <: earliest tile
                bestf[r] = fminf(ob, v);
            }
        }
        // Write next chunk to the OTHER buffer (safe: its last readers were
        // fenced by this iteration's top barrier).
        if (ch + 1 < N_CHUNKS) {
            int4* s = (int4*)(s_buf + ((ch + 1) & 1) * CHUNK_B);
            s[tid] = ra;
            s[512 + tid] = rb;
        }
    }

    // --- Epilogue: reduce across the 32 columns, 3 barriered passes.
    // C/D: col=lane&31, row=(r&3)+8*(r>>2)+4*h. Slots [wave*1024+row*32+col].
    // Pass A: column-best scores -> (b1, bcol, b2).
    __syncthreads();
    float* s_sc = (float*)s_buf;                  // 8*32*32 f32 = 32 KB exactly
#pragma unroll
    for (int r = 0; r < 16; ++r) {
        const int row = (r & 3) + 8 * (r >> 2) + 4 * h;
        s_sc[wave * 1024 + row * 32 + col] = bestf[r];
    }
    __syncthreads();

    float b1 = 3e38f, b2 = 3e38f;
    int bcol = 0;
    if (tid < 256) {
        const int w = tid >> 5, row = tid & 31;
#pragma unroll
        for (int c = 0; c < 32; ++c) {
            const float k = s_sc[w * 1024 + row * 32 + c];
            bcol = (k < b1) ? c : bcol;        // strict <: any col ok (ties flagged)
            b2 = med3f(b1, k, b2);             // 2nd-min of column-bests
            b1 = fminf(b1, k);
        }
    }
    // Pass B: winning tile index.
    __syncthreads();
    uint32_t* s_ti = (uint32_t*)s_buf;
#pragma unroll
    for (int r = 0; r < 16; ++r) {
        const int row = (r & 3) + 8 * (r >> 2) + 4 * h;
        s_ti[wave * 1024 + row * 32 + col] = tidx[r];
    }
    __syncthreads();
    int nwin = 0;
    if (tid < 256) {
        const int w = tid >> 5, row = tid & 31;
        nwin = (int)s_ti[w * 1024 + row * 32 + bcol] * 32 + bcol;
    }
    // Pass C: runner-up within the winning column.
    __syncthreads();
#pragma unroll
    for (int r = 0; r < 16; ++r) {
        const int row = (r & 3) + 8 * (r >> 2) + 4 * h;
        s_sc[wave * 1024 + row * 32 + col] = secf[r];
    }
    __syncthreads();

    if (tid < 256) {
        const int w = tid >> 5, row = tid & 31;
        const float sec_b = s_sc[w * 1024 + row * 32 + bcol];
        const float secondAll = fminf(b2, sec_b);
        const int m = blockIdx.x * 256 + tid;   // = rowBase(w) + row

        bool amb = (secondAll - b1 <= TIE_EPS);
        if (amb) {
            const int pos = atomicAdd(cnt, 1);
            if (pos < list_cap) list[pos] = m;
            else amb = false;                   // overflow: keep screened winner
        }
        if (!amb) {
            const float* cc2 = colors + (size_t)nwin * 3;
            float* o = out + (size_t)m * 3;
            o[0] = cc2[0];
            o[1] = cc2[1];
            o[2] = cc2[2];
        }
    }
}

// ---------------------------------------------------------------------------
// Kernel 3 (rescan): one wave per ambiguous row, fp64 exact (= f64 numpy ref),
// 8192 waves so latency is hidden by TLP; unroll-2 for ILP within a wave.
// ---------------------------------------------------------------------------
__global__ __launch_bounds__(256) void rescan_kernel(
    const float* __restrict__ x_all,
    const float* __restrict__ colors,
    const float* __restrict__ verts,
    const int* __restrict__ cnt,
    const int* __restrict__ list,
    int list_cap,
    float* __restrict__ out)
{
    const int wavesPerBlock = blockDim.x >> 6;
    const int wid  = blockIdx.x * wavesPerBlock + (threadIdx.x >> 6);
    const int lane = threadIdx.x & 63;
    const int nWaves = gridDim.x * wavesPerBlock;

    int ccount = *cnt;
    if (ccount > list_cap) ccount = list_cap;

    for (int rr = wid; rr < ccount; rr += nWaves) {
        const int m = list[rr];
        double bx[D_DIM];
#pragma unroll
        for (int d = 0; d < D_DIM; ++d)
            bx[d] = (double)x_all[(size_t)m * D_DIM + d];

        double best = INFINITY;
        int bi = 0x7fffffff;
#pragma unroll 2
        for (int n = lane; n < N_VERTS; n += 64) {
            const float* y = verts + (size_t)n * D_DIM;
            double dot = 0.0, ys = 0.0;
#pragma unroll
            for (int d = 0; d < D_DIM; ++d) {
                const double yd = (double)y[d];
                dot = fma(bx[d], yd, dot);
                ys  = fma(yd, yd, ys);
            }
            const double s = ys - 2.0 * dot;
            if (s < best || (s == best && n < bi)) { best = s; bi = n; }
        }
#pragma unroll
        for (int off = 32; off > 0; off >>= 1) {
            const double ob = __shfl_xor(best, off, 64);
            const int    oi = __shfl_xor(bi, off, 64);
            if (ob < best || (ob == best && oi < bi)) { best = ob; bi = oi; }
        }
        if (lane == 0) {
            const float* cc = colors + (size_t)bi * 3;
            float* o = out + (size_t)m * 3;
            o[0] = cc[0];
            o[1] = cc[1];
            o[2] = cc[2];
        }
    }
}

// ---------------------------------------------------------------------------
extern "C" void kernel_launch(void* const* d_in, const int* in_sizes, int n_in,
                              void* d_out, int out_size, void* d_ws, size_t ws_size,
                              hipStream_t stream) {
    const float* cse_embedding       = (const float*)d_in[0]; // (M,16)
    const float* verts_colors        = (const float*)d_in[1]; // (N,3)
    const float* verts_cse_embedding = (const float*)d_in[2]; // (N,16)
    float* out = (float*)d_out;                               // (M,3)

    char* ws = (char*)d_ws;
    char*  yfrag = ws + WS_YFRAG_OFF;
    float* ysq   = (float*)(ws + WS_YSQ_OFF);
    int*   cnt   = (int*)(ws + WS_CNT_OFF);
    int*   list  = (int*)(ws + WS_LIST_OFF);
    int list_cap = (int)((ws_size > WS_LIST_OFF)
                         ? ((ws_size - WS_LIST_OFF) / sizeof(int)) : 0);
    if (list_cap > M_ROWS) list_cap = M_ROWS;

    pack_y_kernel<<<(N_TILES * 64) / 256, 256, 0, stream>>>(
        verts_cse_embedding, yfrag, ysq, cnt);

    mfma_screen_kernel<<<M_ROWS / 256, 512, 0, stream>>>(
        cse_embedding, verts_colors, yfrag, ysq, out, cnt, list, list_cap);

    rescan_kernel<<<2048, 256, 0, stream>>>(
        cse_embedding, verts_colors, verts_cse_embedding, cnt, list,
        list_cap, out);
}

// Round 12
// 182.222 us; speedup vs baseline: 1.1139x; 1.1139x over previous
//
#include <hip/hip_runtime.h>
#include <math.h>
#include <stdint.h>

// Problem: M=131072 rows, N=4000 verts (padded to 4096), D=16.
#define M_ROWS   131072
#define N_VERTS  4000
#define N_PAD    4096
#define D_DIM    16
#define N_TILES  (N_PAD / 32)          // 128 n-tiles of 32 verts
#define TILE_B   2048                  // per tile: yh 1KB | yl 1KB
#define CHUNK_T  8                     // tiles per LDS chunk
#define CHUNK_B  (CHUNK_T * TILE_B)    // 16384 B per chunk
#define N_CHUNKS (N_TILES / CHUNK_T)   // 16

// Scores are biased +128 so they are provably positive (score >= -||x||^2 and
// ||x||^2 < 128 for chi^2_16 data at astronomical confidence) -> positive-float
// bit pattern is monotone as u32 -> min_u32 does argmin via packed keys.
#define SCORE_BIAS 128.0f
// key = (score_bits & ~0x7F) | tile (tile 0..127 in SEVEN bits).
// Error budget: 7-bit truncation <= 3.9e-3, dropped al*yl cross term
// <= 4.9e-4, fp32 accum ~2e-4 (ysq injected in EXACT fp32) -> delta <= 4.6e-3.
// TIE_EPS = 0.012 >= 2*delta.
// R11 post-mortem: tightening EPS to 0.002 via exact-fp32 tracking saved only
// ~6 us (rescan at 0.012 is already ~7 us) and cost +45 us in the screen
// (5-op update, 4.4x bank conflicts). EPS line of attack is exhausted.
#define TIE_EPS  0.012f
#define KEY_MASK 0xFFFFFF80u
#define TILE_MASK 0x7Fu

// d_ws layout (bytes):
//   [0      .. 262144)  yfrag : N_TILES x 2048 B, fragment-ordered 32x32 data
//   [262144 .. 278528)  ysq   : N_PAD floats, bias+||y||^2 fp32 (pads 1e30)
//   [278528 .. 278532)  cnt
//   [278592 .. ...   )  list  : ambiguous row indices
#define WS_YFRAG_OFF 0
#define WS_YSQ_OFF   262144
#define WS_CNT_OFF   278528
#define WS_LIST_OFF  278592

typedef float    f32x16 __attribute__((ext_vector_type(16)));
typedef short    s16x8  __attribute__((ext_vector_type(8)));

__device__ __forceinline__ unsigned short f32_to_bf16_rne(float f) {
    unsigned int u = __float_as_uint(f);
    u = (u + 0x7fffu + ((u >> 16) & 1u)) >> 16;
    return (unsigned short)u;
}
__device__ __forceinline__ float bf16_to_f32(unsigned short h) {
    return __uint_as_float(((unsigned int)h) << 16);
}
__device__ __forceinline__ uint32_t umin32(uint32_t a, uint32_t b) { return a < b ? a : b; }
__device__ __forceinline__ uint32_t umax32(uint32_t a, uint32_t b) { return a > b ? a : b; }

// median(a,b,c) in one VALU op. Under the invariant a <= c this equals
// min(c, max(a, b)) -- the second-best update. LLVM can't derive this
// (only valid under the invariant), so force v_med3_u32 via asm.
// Case check (b=new key kb): kb<a -> a; a<=kb<=c -> kb; kb>c -> c.  All match.
// Invariant preserved: min(a,kb) <= min(c, max(a,kb)).  [verified R4, absmax=0]
__device__ __forceinline__ uint32_t med3_u32(uint32_t a, uint32_t b, uint32_t c) {
    uint32_t d;
    asm("v_med3_u32 %0, %1, %2, %3" : "=v"(d) : "v"(a), "v"(b), "v"(c));
    return d;
}

// ---------------------------------------------------------------------------
// Kernel 1: pack Y into 32x32-MFMA fragment order + fp32 biased ysq.
// B-operand layout for mfma_f32_32x32x16_bf16 (verified R1/R2, absmax=0):
// B[n = lane&31][k = (lane>>5)*8 + j].
// Per tile T (32 verts): yh frag (64 lanes x 16B) | yl frag.
// One thread per (tile, lane) = 8192 threads.  [unchanged from R8, verified]
// ---------------------------------------------------------------------------
__global__ void pack_y_kernel(const float* __restrict__ verts,
                              char* __restrict__ yfrag,
                              float* __restrict__ ysq,
                              int* __restrict__ cnt) {
    const int tid = blockIdx.x * blockDim.x + threadIdx.x;   // 0..8191
    if (tid == 0) *cnt = 0;

    const int T   = tid >> 6;
    const int l   = tid & 63;
    const int col = l & 31;
    const int h   = l >> 5;
    const int n   = T * 32 + col;
    const int d0  = h * 8;

    float v[8];
    if (n < N_VERTS) {
        const float* y = verts + (size_t)n * D_DIM + d0;
#pragma unroll
        for (int j = 0; j < 8; ++j) v[j] = y[j];
    } else {
#pragma unroll
        for (int j = 0; j < 8; ++j) v[j] = 0.f;
    }
    s16x8 fh, fl;
#pragma unroll
    for (int j = 0; j < 8; ++j) {
        const unsigned short hh = f32_to_bf16_rne(v[j]);
        fh[j] = (short)hh;
        fl[j] = (short)f32_to_bf16_rne(v[j] - bf16_to_f32(hh));
    }
    char* tb = yfrag + (size_t)T * TILE_B + (size_t)l * 16;
    *(s16x8*)(tb)        = fh;
    *(s16x8*)(tb + 1024) = fl;

    // ysq: fp32, bias baked in; pad columns get 1e30 so they never win.
    if (tid < N_PAD) {
        float ys;
        if (tid < N_VERTS) {
            ys = SCORE_BIAS;
            const float* y = verts + (size_t)tid * D_DIM;
#pragma unroll
            for (int d = 0; d < D_DIM; ++d) ys = fmaf(y[d], y[d], ys);
        } else {
            ys = 1e30f;
        }
        ysq[tid] = ys;
    }
}

// ---------------------------------------------------------------------------
// Kernel 2 (MFMA screen, 32x32x16): 512 thr = 8 waves, wave = 32 rows x all n.
// R8 structure (verified 86.4 us): CHUNK_T=8, launch_bounds(512,4),
// reg-prefetch double-buffered LDS, one barrier per chunk, ysq via fp32 acc
// init, packed 7-bit keys, med3 second-tracking.
//
// R12: LOAD-ROTATED tile loop. R8 model: ~190 issue-cyc/tile/wave vs 209k-cyc
// wall -> exposed ds_read latency is serial with each tile's MFMA+VALU chain
// (unroll-1 puts the loads at the iteration top). Rotate byh/byl/ysn one tile
// ahead: tile t+1's loads issue BEFORE tile t's MFMA chain and key-update,
// hiding ~120 cyc/tile under ~220 cyc of work. Only the loads are pipelined
// (+9 regs); the tracker chain stays single-stream (R5's failure was doubling
// acc+trackers, not the idea of overlap).
//
// History: R6 do NOT raise min-waves (VGPR squeeze -> spill). R3:
// global_load_lds staging FAILED correctness. R5: 2-tile full ILP regressed.
// R9/R10: AGPR-shuttle theory refuted (pins + asm-VGPR MFMA both null).
// R11: exact-fp32 tracking regressed (5-op update, 4.4x bank conflicts).
// `#pragma unroll 1`: full unroll -> spill (R1). Spill tripwire: FETCH <20MB.
// ---------------------------------------------------------------------------
__global__ __launch_bounds__(512, 4) void mfma_screen_kernel(
    const float* __restrict__ x_all,    // (M,16)
    const float* __restrict__ colors,   // (N,3)
    const char* __restrict__ yfrag,     // N_TILES x 2048 B
    const float* __restrict__ ysqg,     // N_PAD fp32 (biased)
    float* __restrict__ out,            // (M,3)
    int* __restrict__ cnt,
    int* __restrict__ list,
    int list_cap)
{
    __shared__ __align__(16) char  s_buf[2 * CHUNK_B];   // 32 KB (reused for reduce)
    __shared__ __align__(16) float s_ysq[N_PAD];         // 16 KB

    const int tid  = threadIdx.x;
    const int wave = tid >> 6;
    const int lane = tid & 63;
    const int col  = lane & 31;          // A row / B col / C-D col
    const int h    = lane >> 5;          // k-half select
    const int rowBase = blockIdx.x * 256 + wave * 32;

    // --- A fragments (built once). Lane supplies A[m=col][k=h*8+j].
    const float* xr = x_all + (size_t)(rowBase + col) * D_DIM + h * 8;
    const float4 xa = *(const float4*)xr;
    const float4 xb = *(const float4*)(xr + 4);
    const float xv[8] = {xa.x, xa.y, xa.z, xa.w, xb.x, xb.y, xb.z, xb.w};
    s16x8 a1, a2;
#pragma unroll
    for (int j = 0; j < 8; ++j) {
        const float a = -2.0f * xv[j];
        const unsigned short hh = f32_to_bf16_rne(a);
        a1[j] = (short)hh;
        a2[j] = (short)f32_to_bf16_rne(a - bf16_to_f32(hh));
    }

    // --- Stage ysq once (1024 int4, 2 per thread). Fenced by first barrier.
    {
        const int4* g = (const int4*)ysqg;
        int4* s = (int4*)s_ysq;
        s[tid] = g[tid];
        s[tid + 512] = g[tid + 512];
    }
    // --- Prologue: chunk 0 -> buf0 (stride-16B per thread: conflict-free).
    const int4* gy = (const int4*)yfrag;
    int4 ra = gy[tid];
    int4 rb = gy[512 + tid];
    {
        int4* s = (int4*)s_buf;
        s[tid] = ra;
        s[512 + tid] = rb;
    }

    uint32_t best[16], second[16];
#pragma unroll
    for (int r = 0; r < 16; ++r) { best[r] = 0xFFFFFFFFu; second[r] = 0xFFFFFFFFu; }

    for (int ch = 0; ch < N_CHUNKS; ++ch) {
        // Prefetch next chunk into regs BEFORE the barrier (latency overlap).
        if (ch + 1 < N_CHUNKS) {
            ra = gy[(ch + 1) * 1024 + tid];
            rb = gy[(ch + 1) * 1024 + 512 + tid];
        }
        __syncthreads();   // buf[ch&1] writes (prev iter / prologue) visible

        const char*  bb    = s_buf + (ch & 1) * CHUNK_B + lane * 16;
        const float* ysrow = s_ysq + ch * CHUNK_T * 32 + col;

        // Load-rotated pipeline: tile t's fragments are in regs before the
        // iteration starts; t+1's loads issue before t's MFMA+VALU.
        s16x8 byh = *(const s16x8*)(bb);
        s16x8 byl = *(const s16x8*)(bb + 1024);
        float ysn = ysrow[0];
#pragma unroll 1
        for (int t = 0; t < CHUNK_T; ++t) {
            s16x8 byh_n, byl_n;
            float ysn_n;
            if (t + 1 < CHUNK_T) {
                byh_n = *(const s16x8*)(bb + (t + 1) * TILE_B);
                byl_n = *(const s16x8*)(bb + (t + 1) * TILE_B + 1024);
                ysn_n = ysrow[(t + 1) * 32];
            }
            f32x16 acc;
#pragma unroll
            for (int r = 0; r < 16; ++r) acc[r] = ysn;
            acc = __builtin_amdgcn_mfma_f32_32x32x16_bf16(a1, byh, acc, 0, 0, 0);
            acc = __builtin_amdgcn_mfma_f32_32x32x16_bf16(a2, byh, acc, 0, 0, 0);
            acc = __builtin_amdgcn_mfma_f32_32x32x16_bf16(a1, byl, acc, 0, 0, 0);
            // Pin acc to arch VGPRs (kept identical to verified R8 build).
            asm volatile("" : "+v"(acc));
            const uint32_t tcur = (uint32_t)(ch * CHUNK_T + t);
#pragma unroll
            for (int r = 0; r < 16; ++r) {
                const uint32_t kb = (__float_as_uint(acc[r]) & KEY_MASK) | tcur;
                second[r] = med3_u32(best[r], kb, second[r]);  // = min(sec, max(best,kb))
                best[r]   = umin32(best[r], kb);
            }
            if (t + 1 < CHUNK_T) {
                byh = byh_n;
                byl = byl_n;
                ysn = ysn_n;
            }
        }
        // Write next chunk to the OTHER buffer (safe: its last readers were
        // fenced by this iteration's top barrier).
        if (ch + 1 < N_CHUNKS) {
            int4* s = (int4*)(s_buf + ((ch + 1) & 1) * CHUNK_B);
            s[tid] = ra;
            s[512 + tid] = rb;
        }
    }

    // --- Reduce across the 32 columns. C/D: col=lane&31,
    // row=(r&3)+8*(r>>2)+4*h. Reuse s_buf: keys [wave*1024 + row*32 + col].
    __syncthreads();
    uint32_t* s_red = (uint32_t*)s_buf;            // 8*32*32 u32 = 32 KB exactly
#pragma unroll
    for (int r = 0; r < 16; ++r) {
        const int row = (r & 3) + 8 * (r >> 2) + 4 * h;
        s_red[wave * 1024 + row * 32 + col] = best[r];
    }
    __syncthreads();

    uint32_t b1 = 0xFFFFFFFFu, b2 = 0xFFFFFFFFu;
    int cwin = 0;
    if (tid < 256) {
        const int w = tid >> 5, row = tid & 31;
#pragma unroll
        for (int c = 0; c < 32; ++c) {
            const uint32_t k = s_red[w * 1024 + row * 32 + c];
            cwin = (k < b1) ? c : cwin;         // strict <: earliest col on equal keys
            b2 = umin32(b2, umax32(b1, k));     // 2nd-min of bests
            b1 = umin32(b1, k);
        }
    }
    __syncthreads();
#pragma unroll
    for (int r = 0; r < 16; ++r) {
        const int row = (r & 3) + 8 * (r >> 2) + 4 * h;
        s_red[wave * 1024 + row * 32 + col] = second[r];
    }
    __syncthreads();

    if (tid < 256) {
        const int w = tid >> 5, row = tid & 31;
        uint32_t smin = 0xFFFFFFFFu;
#pragma unroll
        for (int c = 0; c < 32; ++c)
            smin = umin32(smin, s_red[w * 1024 + row * 32 + c]);
        const uint32_t secondAll = umin32(smin, b2);
        const float s1 = __uint_as_float(b1 & KEY_MASK);
        const float s2 = __uint_as_float(secondAll & KEY_MASK);
        const int n = (int)(b1 & TILE_MASK) * 32 + cwin;
        const int m = blockIdx.x * 256 + tid;   // = rowBase(w) + row

        bool amb = (s2 - s1 <= TIE_EPS);
        if (amb) {
            const int pos = atomicAdd(cnt, 1);
            if (pos < list_cap) list[pos] = m;
            else amb = false;                   // overflow: keep screened winner
        }
        if (!amb) {
            const float* cc2 = colors + (size_t)n * 3;
            float* o = out + (size_t)m * 3;
            o[0] = cc2[0];
            o[1] = cc2[1];
            o[2] = cc2[2];
        }
    }
}

// ---------------------------------------------------------------------------
// Kernel 3 (rescan): one wave per ambiguous row, fp64 exact (= f64 numpy ref),
// 8192 waves so latency is hidden by TLP; unroll-2 for ILP within a wave.
// ---------------------------------------------------------------------------
__global__ __launch_bounds__(256) void rescan_kernel(
    const float* __restrict__ x_all,
    const float* __restrict__ colors,
    const float* __restrict__ verts,
    const int* __restrict__ cnt,
    const int* __restrict__ list,
    int list_cap,
    float* __restrict__ out)
{
    const int wavesPerBlock = blockDim.x >> 6;
    const int wid  = blockIdx.x * wavesPerBlock + (threadIdx.x >> 6);
    const int lane = threadIdx.x & 63;
    const int nWaves = gridDim.x * wavesPerBlock;

    int ccount = *cnt;
    if (ccount > list_cap) ccount = list_cap;

    for (int rr = wid; rr < ccount; rr += nWaves) {
        const int m = list[rr];
        double bx[D_DIM];
#pragma unroll
        for (int d = 0; d < D_DIM; ++d)
            bx[d] = (double)x_all[(size_t)m * D_DIM + d];

        double best = INFINITY;
        int bi = 0x7fffffff;
#pragma unroll 2
        for (int n = lane; n < N_VERTS; n += 64) {
            const float* y = verts + (size_t)n * D_DIM;
            double dot = 0.0, ys = 0.0;
#pragma unroll
            for (int d = 0; d < D_DIM; ++d) {
                const double yd = (double)y[d];
                dot = fma(bx[d], yd, dot);
                ys  = fma(yd, yd, ys);
            }
            const double s = ys - 2.0 * dot;
            if (s < best || (s == best && n < bi)) { best = s; bi = n; }
        }
#pragma unroll
        for (int off = 32; off > 0; off >>= 1) {
            const double ob = __shfl_xor(best, off, 64);
            const int    oi = __shfl_xor(bi, off, 64);
            if (ob < best || (ob == best && oi < bi)) { best = ob; bi = oi; }
        }
        if (lane == 0) {
            const float* cc = colors + (size_t)bi * 3;
            float* o = out + (size_t)m * 3;
            o[0] = cc[0];
            o[1] = cc[1];
            o[2] = cc[2];
        }
    }
}

// ---------------------------------------------------------------------------
extern "C" void kernel_launch(void* const* d_in, const int* in_sizes, int n_in,
                              void* d_out, int out_size, void* d_ws, size_t ws_size,
                              hipStream_t stream) {
    const float* cse_embedding       = (const float*)d_in[0]; // (M,16)
    const float* verts_colors        = (const float*)d_in[1]; // (N,3)
    const float* verts_cse_embedding = (const float*)d_in[2]; // (N,16)
    float* out = (float*)d_out;                               // (M,3)

    char* ws = (char*)d_ws;
    char*  yfrag = ws + WS_YFRAG_OFF;
    float* ysq   = (float*)(ws + WS_YSQ_OFF);
    int*   cnt   = (int*)(ws + WS_CNT_OFF);
    int*   list  = (int*)(ws + WS_LIST_OFF);
    int list_cap = (int)((ws_size > WS_LIST_OFF)
                         ? ((ws_size - WS_LIST_OFF) / sizeof(int)) : 0);
    if (list_cap > M_ROWS) list_cap = M_ROWS;

    pack_y_kernel<<<(N_TILES * 64) / 256, 256, 0, stream>>>(
        verts_cse_embedding, yfrag, ysq, cnt);

    mfma_screen_kernel<<<M_ROWS / 256, 512, 0, stream>>>(
        cse_embedding, verts_colors, yfrag, ysq, out, cnt, list, list_cap);

    rescan_kernel<<<2048, 256, 0, stream>>>(
        cse_embedding, verts_colors, verts_cse_embedding, cnt, list,
        list_cap, out);
}

// Round 13
// 164.573 us; speedup vs baseline: 1.2333x; 1.1072x over previous
//
#include <hip/hip_runtime.h>
#include <math.h>
#include <stdint.h>

// Problem: M=131072 rows, N=4000 verts (padded to 4096), D=16.
#define M_ROWS   131072
#define N_VERTS  4000
#define N_PAD    4096
#define D_DIM    16
#define N_TILES  (N_PAD / 32)          // 128 n-tiles of 32 verts
#define TILE_B   2048                  // per tile: yh 1KB | yl 1KB
#define CHUNK_T  8                     // tiles per LDS chunk
#define CHUNK_B  (CHUNK_T * TILE_B)    // 16384 B per chunk
#define N_CHUNKS (N_TILES / CHUNK_T)   // 16

// Scores are biased +128 so they are provably positive (score >= -||x||^2 and
// ||x||^2 < 128 for chi^2_16 data at astronomical confidence) -> positive-float
// bit pattern is monotone as u32 -> min_u32 does argmin via packed keys.
#define SCORE_BIAS 128.0f
// key = (score_bits & ~0x7F) | tile (tile 0..127 in SEVEN bits).
// Error budget: 7-bit truncation <= 3.9e-3, dropped al*yl cross term
// <= 4.9e-4, fp32 accum ~2e-4 (ysq injected in EXACT fp32) -> delta <= 4.6e-3.
// TIE_EPS = 0.012 >= 2*delta.
// R11: tightening EPS to 0.002 (exact-fp32 tracking) saved only ~6 us and
// cost +45 us in the screen. EPS line of attack is exhausted.
#define TIE_EPS  0.012f
#define KEY_MASK 0xFFFFFF80u
#define TILE_MASK 0x7Fu

// d_ws layout (bytes):
//   [0      .. 262144)  yfrag : N_TILES x 2048 B, fragment-ordered 32x32 data
//   [262144 .. 278528)  ysq   : N_PAD floats, bias+||y||^2 fp32 (pads 1e30)
//   [278528 .. 278532)  cnt
//   [278592 .. ...   )  list  : ambiguous row indices
#define WS_YFRAG_OFF 0
#define WS_YSQ_OFF   262144
#define WS_CNT_OFF   278528
#define WS_LIST_OFF  278592

typedef float    f32x16 __attribute__((ext_vector_type(16)));
typedef short    s16x8  __attribute__((ext_vector_type(8)));

__device__ __forceinline__ unsigned short f32_to_bf16_rne(float f) {
    unsigned int u = __float_as_uint(f);
    u = (u + 0x7fffu + ((u >> 16) & 1u)) >> 16;
    return (unsigned short)u;
}
__device__ __forceinline__ float bf16_to_f32(unsigned short h) {
    return __uint_as_float(((unsigned int)h) << 16);
}
__device__ __forceinline__ uint32_t umin32(uint32_t a, uint32_t b) { return a < b ? a : b; }
__device__ __forceinline__ uint32_t umax32(uint32_t a, uint32_t b) { return a > b ? a : b; }

// median(a,b,c) in one VALU op. Under the invariant a <= c this equals
// min(c, max(a, b)) -- the second-best update. LLVM can't derive this
// (only valid under the invariant), so force v_med3_u32 via asm.
// Case check (b=new key kb): kb<a -> a; a<=kb<=c -> kb; kb>c -> c.  All match.
// Invariant preserved: min(a,kb) <= min(c, max(a,kb)).  [verified R4, absmax=0]
__device__ __forceinline__ uint32_t med3_u32(uint32_t a, uint32_t b, uint32_t c) {
    uint32_t d;
    asm("v_med3_u32 %0, %1, %2, %3" : "=v"(d) : "v"(a), "v"(b), "v"(c));
    return d;
}

// ---------------------------------------------------------------------------
// Kernel 1: pack Y into 32x32-MFMA fragment order + fp32 biased ysq.
// B-operand layout for mfma_f32_32x32x16_bf16 (verified R1/R2, absmax=0):
// B[n = lane&31][k = (lane>>5)*8 + j].
// Per tile T (32 verts): yh frag (64 lanes x 16B) | yl frag.
// One thread per (tile, lane) = 8192 threads.
// ---------------------------------------------------------------------------
__global__ void pack_y_kernel(const float* __restrict__ verts,
                              char* __restrict__ yfrag,
                              float* __restrict__ ysq,
                              int* __restrict__ cnt) {
    const int tid = blockIdx.x * blockDim.x + threadIdx.x;   // 0..8191
    if (tid == 0) *cnt = 0;

    const int T   = tid >> 6;
    const int l   = tid & 63;
    const int col = l & 31;
    const int h   = l >> 5;
    const int n   = T * 32 + col;
    const int d0  = h * 8;

    float v[8];
    if (n < N_VERTS) {
        const float* y = verts + (size_t)n * D_DIM + d0;
#pragma unroll
        for (int j = 0; j < 8; ++j) v[j] = y[j];
    } else {
#pragma unroll
        for (int j = 0; j < 8; ++j) v[j] = 0.f;
    }
    s16x8 fh, fl;
#pragma unroll
    for (int j = 0; j < 8; ++j) {
        const unsigned short hh = f32_to_bf16_rne(v[j]);
        fh[j] = (short)hh;
        fl[j] = (short)f32_to_bf16_rne(v[j] - bf16_to_f32(hh));
    }
    char* tb = yfrag + (size_t)T * TILE_B + (size_t)l * 16;
    *(s16x8*)(tb)        = fh;
    *(s16x8*)(tb + 1024) = fl;

    // ysq: fp32, bias baked in; pad columns get 1e30 so they never win.
    if (tid < N_PAD) {
        float ys;
        if (tid < N_VERTS) {
            ys = SCORE_BIAS;
            const float* y = verts + (size_t)tid * D_DIM;
#pragma unroll
            for (int d = 0; d < D_DIM; ++d) ys = fmaf(y[d], y[d], ys);
        } else {
            ys = 1e30f;
        }
        ysq[tid] = ys;
    }
}

// ---------------------------------------------------------------------------
// Kernel 2 (MFMA screen, 32x32x16): 512 thr = 8 waves, wave = 32 rows x all n.
// R8 structure (verified 86.4 us screen / 164.0 us total -- session best):
// CHUNK_T=8, launch_bounds(512,4), reg-prefetch double-buffered LDS, one
// barrier per chunk, ysq via fp32 acc init, packed 7-bit keys, med3 second.
//
// Full failure ledger (do not retry without new evidence):
//   R1:  full tile-loop unroll -> ~224 transient VGPR -> scratch spill.
//   R3:  global_load_lds DMA staging -> WRONG RESULTS (absmax 0.97).
//   R5:  2-tile ILP (dual acc+trackers) -> regression (serial best[] RAW).
//   R6:  launch_bounds(512,8) split-K -> VGPR squeeze to 32 -> spill, 2.8x.
//   R9:  "+v" ext-vector pin -> null (allocator optimizes it away).
//   R10: asm-VGPR MFMA chain -> null (AGPR-shuttle theory refuted).
//   R11: exact-fp32 tracking (5-op update) -> +45 us, 4.4x bank conflicts.
//   R12: load-rotated pipeline -> +19 us (rotation movs > latency hidden).
// Floor arithmetic: key updates are shape-invariant: M*N_PAD = 537M element
// updates x 4 VALU / 64 lanes / 1024 SIMDs * 2cyc ~= 27 us VALU floor +
// ~20 us MFMA; measured 86 us = floor + exposed per-tile serial chain
// (ds_read -> 3 chained MFMA -> key VALU) that 5 overlap strategies failed
// to shorten at 4 waves/SIMD (per-wave state caps occupancy).
// ---------------------------------------------------------------------------
__global__ __launch_bounds__(512, 4) void mfma_screen_kernel(
    const float* __restrict__ x_all,    // (M,16)
    const float* __restrict__ colors,   // (N,3)
    const char* __restrict__ yfrag,     // N_TILES x 2048 B
    const float* __restrict__ ysqg,     // N_PAD fp32 (biased)
    float* __restrict__ out,            // (M,3)
    int* __restrict__ cnt,
    int* __restrict__ list,
    int list_cap)
{
    __shared__ __align__(16) char  s_buf[2 * CHUNK_B];   // 32 KB (reused for reduce)
    __shared__ __align__(16) float s_ysq[N_PAD];         // 16 KB

    const int tid  = threadIdx.x;
    const int wave = tid >> 6;
    const int lane = tid & 63;
    const int col  = lane & 31;          // A row / B col / C-D col
    const int h    = lane >> 5;          // k-half select
    const int rowBase = blockIdx.x * 256 + wave * 32;

    // --- A fragments (built once). Lane supplies A[m=col][k=h*8+j].
    const float* xr = x_all + (size_t)(rowBase + col) * D_DIM + h * 8;
    const float4 xa = *(const float4*)xr;
    const float4 xb = *(const float4*)(xr + 4);
    const float xv[8] = {xa.x, xa.y, xa.z, xa.w, xb.x, xb.y, xb.z, xb.w};
    s16x8 a1, a2;
#pragma unroll
    for (int j = 0; j < 8; ++j) {
        const float a = -2.0f * xv[j];
        const unsigned short hh = f32_to_bf16_rne(a);
        a1[j] = (short)hh;
        a2[j] = (short)f32_to_bf16_rne(a - bf16_to_f32(hh));
    }

    // --- Stage ysq once (1024 int4, 2 per thread). Fenced by first barrier.
    {
        const int4* g = (const int4*)ysqg;
        int4* s = (int4*)s_ysq;
        s[tid] = g[tid];
        s[tid + 512] = g[tid + 512];
    }
    // --- Prologue: chunk 0 -> buf0 (stride-16B per thread: conflict-free).
    const int4* gy = (const int4*)yfrag;
    int4 ra = gy[tid];
    int4 rb = gy[512 + tid];
    {
        int4* s = (int4*)s_buf;
        s[tid] = ra;
        s[512 + tid] = rb;
    }

    uint32_t best[16], second[16];
#pragma unroll
    for (int r = 0; r < 16; ++r) { best[r] = 0xFFFFFFFFu; second[r] = 0xFFFFFFFFu; }

    for (int ch = 0; ch < N_CHUNKS; ++ch) {
        // Prefetch next chunk into regs BEFORE the barrier (latency overlap).
        if (ch + 1 < N_CHUNKS) {
            ra = gy[(ch + 1) * 1024 + tid];
            rb = gy[(ch + 1) * 1024 + 512 + tid];
        }
        __syncthreads();   // buf[ch&1] writes (prev iter / prologue) visible

        const char*  bb    = s_buf + (ch & 1) * CHUNK_B + lane * 16;
        const float* ysrow = s_ysq + ch * CHUNK_T * 32 + col;
#pragma unroll 1
        for (int t = 0; t < CHUNK_T; ++t) {
            const s16x8 byh = *(const s16x8*)(bb + t * TILE_B);          // conflict-free
            const s16x8 byl = *(const s16x8*)(bb + t * TILE_B + 1024);
            const float ysn = ysrow[t * 32];   // per-lane scalar; lanes l/l+32 broadcast
            f32x16 acc;
#pragma unroll
            for (int r = 0; r < 16; ++r) acc[r] = ysn;
            acc = __builtin_amdgcn_mfma_f32_32x32x16_bf16(a1, byh, acc, 0, 0, 0);
            acc = __builtin_amdgcn_mfma_f32_32x32x16_bf16(a2, byh, acc, 0, 0, 0);
            acc = __builtin_amdgcn_mfma_f32_32x32x16_bf16(a1, byl, acc, 0, 0, 0);
            // Pin acc to arch VGPRs (part of the verified R8 build).
            asm volatile("" : "+v"(acc));
            const uint32_t tcur = (uint32_t)(ch * CHUNK_T + t);
#pragma unroll
            for (int r = 0; r < 16; ++r) {
                const uint32_t kb = (__float_as_uint(acc[r]) & KEY_MASK) | tcur;
                second[r] = med3_u32(best[r], kb, second[r]);  // = min(sec, max(best,kb))
                best[r]   = umin32(best[r], kb);
            }
        }
        // Write next chunk to the OTHER buffer (safe: its last readers were
        // fenced by this iteration's top barrier).
        if (ch + 1 < N_CHUNKS) {
            int4* s = (int4*)(s_buf + ((ch + 1) & 1) * CHUNK_B);
            s[tid] = ra;
            s[512 + tid] = rb;
        }
    }

    // --- Reduce across the 32 columns. C/D: col=lane&31,
    // row=(r&3)+8*(r>>2)+4*h. Reuse s_buf: keys [wave*1024 + row*32 + col].
    __syncthreads();
    uint32_t* s_red = (uint32_t*)s_buf;            // 8*32*32 u32 = 32 KB exactly
#pragma unroll
    for (int r = 0; r < 16; ++r) {
        const int row = (r & 3) + 8 * (r >> 2) + 4 * h;
        s_red[wave * 1024 + row * 32 + col] = best[r];
    }
    __syncthreads();

    uint32_t b1 = 0xFFFFFFFFu, b2 = 0xFFFFFFFFu;
    int cwin = 0;
    if (tid < 256) {
        const int w = tid >> 5, row = tid & 31;
#pragma unroll
        for (int c = 0; c < 32; ++c) {
            const uint32_t k = s_red[w * 1024 + row * 32 + c];
            cwin = (k < b1) ? c : cwin;         // strict <: earliest col on equal keys
            b2 = umin32(b2, umax32(b1, k));     // 2nd-min of bests
            b1 = umin32(b1, k);
        }
    }
    __syncthreads();
#pragma unroll
    for (int r = 0; r < 16; ++r) {
        const int row = (r & 3) + 8 * (r >> 2) + 4 * h;
        s_red[wave * 1024 + row * 32 + col] = second[r];
    }
    __syncthreads();

    if (tid < 256) {
        const int w = tid >> 5, row = tid & 31;
        uint32_t smin = 0xFFFFFFFFu;
#pragma unroll
        for (int c = 0; c < 32; ++c)
            smin = umin32(smin, s_red[w * 1024 + row * 32 + c]);
        const uint32_t secondAll = umin32(smin, b2);
        const float s1 = __uint_as_float(b1 & KEY_MASK);
        const float s2 = __uint_as_float(secondAll & KEY_MASK);
        const int n = (int)(b1 & TILE_MASK) * 32 + cwin;
        const int m = blockIdx.x * 256 + tid;   // = rowBase(w) + row

        bool amb = (s2 - s1 <= TIE_EPS);
        if (amb) {
            const int pos = atomicAdd(cnt, 1);
            if (pos < list_cap) list[pos] = m;
            else amb = false;                   // overflow: keep screened winner
        }
        if (!amb) {
            const float* cc2 = colors + (size_t)n * 3;
            float* o = out + (size_t)m * 3;
            o[0] = cc2[0];
            o[1] = cc2[1];
            o[2] = cc2[2];
        }
    }
}

// ---------------------------------------------------------------------------
// Kernel 3 (rescan): one wave per ambiguous row, fp64 exact (= f64 numpy ref),
// 8192 waves so latency is hidden by TLP; unroll-2 for ILP within a wave.
// ---------------------------------------------------------------------------
__global__ __launch_bounds__(256) void rescan_kernel(
    const float* __restrict__ x_all,
    const float* __restrict__ colors,
    const float* __restrict__ verts,
    const int* __restrict__ cnt,
    const int* __restrict__ list,
    int list_cap,
    float* __restrict__ out)
{
    const int wavesPerBlock = blockDim.x >> 6;
    const int wid  = blockIdx.x * wavesPerBlock + (threadIdx.x >> 6);
    const int lane = threadIdx.x & 63;
    const int nWaves = gridDim.x * wavesPerBlock;

    int ccount = *cnt;
    if (ccount > list_cap) ccount = list_cap;

    for (int rr = wid; rr < ccount; rr += nWaves) {
        const int m = list[rr];
        double bx[D_DIM];
#pragma unroll
        for (int d = 0; d < D_DIM; ++d)
            bx[d] = (double)x_all[(size_t)m * D_DIM + d];

        double best = INFINITY;
        int bi = 0x7fffffff;
#pragma unroll 2
        for (int n = lane; n < N_VERTS; n += 64) {
            const float* y = verts + (size_t)n * D_DIM;
            double dot = 0.0, ys = 0.0;
#pragma unroll
            for (int d = 0; d < D_DIM; ++d) {
                const double yd = (double)y[d];
                dot = fma(bx[d], yd, dot);
                ys  = fma(yd, yd, ys);
            }
            const double s = ys - 2.0 * dot;
            if (s < best || (s == best && n < bi)) { best = s; bi = n; }
        }
#pragma unroll
        for (int off = 32; off > 0; off >>= 1) {
            const double ob = __shfl_xor(best, off, 64);
            const int    oi = __shfl_xor(bi, off, 64);
            if (ob < best || (ob == best && oi < bi)) { best = ob; bi = oi; }
        }
        if (lane == 0) {
            const float* cc = colors + (size_t)bi * 3;
            float* o = out + (size_t)m * 3;
            o[0] = cc[0];
            o[1] = cc[1];
            o[2] = cc[2];
        }
    }
}

// ---------------------------------------------------------------------------
extern "C" void kernel_launch(void* const* d_in, const int* in_sizes, int n_in,
                              void* d_out, int out_size, void* d_ws, size_t ws_size,
                              hipStream_t stream) {
    const float* cse_embedding       = (const float*)d_in[0]; // (M,16)
    const float* verts_colors        = (const float*)d_in[1]; // (N,3)
    const float* verts_cse_embedding = (const float*)d_in[2]; // (N,16)
    float* out = (float*)d_out;                               // (M,3)

    char* ws = (char*)d_ws;
    char*  yfrag = ws + WS_YFRAG_OFF;
    float* ysq   = (float*)(ws + WS_YSQ_OFF);
    int*   cnt   = (int*)(ws + WS_CNT_OFF);
    int*   list  = (int*)(ws + WS_LIST_OFF);
    int list_cap = (int)((ws_size > WS_LIST_OFF)
                         ? ((ws_size - WS_LIST_OFF) / sizeof(int)) : 0);
    if (list_cap > M_ROWS) list_cap = M_ROWS;

    pack_y_kernel<<<(N_TILES * 64) / 256, 256, 0, stream>>>(
        verts_cse_embedding, yfrag, ysq, cnt);

    mfma_screen_kernel<<<M_ROWS / 256, 512, 0, stream>>>(
        cse_embedding, verts_colors, yfrag, ysq, out, cnt, list, list_cap);

    rescan_kernel<<<2048, 256, 0, stream>>>(
        cse_embedding, verts_colors, verts_cse_embedding, cnt, list,
        list_cap, out);
}